// Round 12
// baseline (114.055 us; speedup 1.0000x reference)
//
#include <hip/hip_runtime.h>

#define N_NODES 50000
#define N_EDGES 600000
#define DIM 128
#define NB_G 3125              // 16-node buckets (= gather blocks; 50000/16 exact)
#define NJ 782                 // hist/scatter partition blocks
#define EPB 768                // edges per partition block: 782*768 = 600576
#define GCAP 512               // gather LDS sort capacity (mean 192, sd 13.9 -> 23 sigma)

typedef short bf16x8 __attribute__((ext_vector_type(8)));
typedef float f32x4 __attribute__((ext_vector_type(4)));

__device__ __forceinline__ float bf2f(unsigned short u) {
    union { unsigned int i; float f; } x; x.i = ((unsigned int)u) << 16; return x.f;
}
__device__ __forceinline__ unsigned short f2bf(float f) {
    union { float f; unsigned int i; } x; x.f = f;
    unsigned int r = x.i + 0x7FFFu + ((x.i >> 16) & 1u);   // RNE
    return (unsigned short)(r >> 16);
}

// ---------------- MFMA GEMM (256 thr, 782 blocks) + fused 16-node-bucket histogram ----------------
// h[n][d] = bf16( sum_k x[n][k] * W[d][k] ). Histogram counters: two u16 packed
// per u32 LDS word (6.3 KB) so total LDS stays 38.3 KB -> 4 blocks/CU.
__global__ __launch_bounds__(256) void gemm_kernel(const float* __restrict__ x,
                                                   const float* __restrict__ W,
                                                   unsigned short* __restrict__ h,
                                                   const int* __restrict__ rows,
                                                   unsigned short* __restrict__ Hm16,
                                                   int* __restrict__ done) {
    __shared__ unsigned char Wl[128 * 256];        // bf16[128 dims][128 k], swizzled
    __shared__ unsigned int cnt32[(NB_G + 1) / 2]; // 1563 u32 = 3126 packed u16
    const int tid = threadIdx.x;

    if (Hm16) {
        for (int i = tid; i < (NB_G + 1) / 2; i += 256) cnt32[i] = 0;
        if (blockIdx.x == 0 && tid == 0) *done = 0;    // reset scanAB's counter
    }

    // ---- stage W -> LDS bf16 (swizzled): 4096 float4 chunks, 16 per thread
#pragma unroll
    for (int i = 0; i < 16; ++i) {
        int c  = tid + i * 256;
        int od = c >> 5;
        int kg = c & 31;
        float4 w = *((const float4*)(W + od * DIM) + kg);
        unsigned int lo = (unsigned int)f2bf(w.x) | ((unsigned int)f2bf(w.y) << 16);
        unsigned int hi = (unsigned int)f2bf(w.z) | ((unsigned int)f2bf(w.w) << 16);
        int byte = od * 256 + ((kg * 8) ^ ((od & 7) << 4));
        *reinterpret_cast<uint2*>(Wl + byte) = make_uint2(lo, hi);
    }

    // ---- load + convert this wave's x rows (node = lane&15, k-slot q = lane>>4)
    const int lane = tid & 63;
    const int wv   = tid >> 6;
    const int q    = lane >> 4;
    const int node = blockIdx.x * 64 + wv * 16 + (lane & 15);
    const int ncl  = node < N_NODES ? node : N_NODES - 1;

    bf16x8 xb[4];
#pragma unroll
    for (int s = 0; s < 4; ++s) {
        const float* xp = x + (size_t)ncl * DIM + s * 32 + q * 8;
        float4 x0 = *(const float4*)(xp);
        float4 x1 = *(const float4*)(xp + 4);
        bf16x8 v;
        v[0] = (short)f2bf(x0.x); v[1] = (short)f2bf(x0.y);
        v[2] = (short)f2bf(x0.z); v[3] = (short)f2bf(x0.w);
        v[4] = (short)f2bf(x1.x); v[5] = (short)f2bf(x1.y);
        v[6] = (short)f2bf(x1.z); v[7] = (short)f2bf(x1.w);
        xb[s] = v;
    }

    __syncthreads();   // cnt32 zeroed + W staged

    // ---- fused histogram: packed LDS atomics (768 edges/block)
    if (Hm16) {
        int ebase = blockIdx.x * EPB;
#pragma unroll
        for (int i = 0; i < 3; ++i) {
            int e = ebase + tid + i * 256;
            if (e < N_EDGES) {
                int b = rows[e] >> 4;
                atomicAdd(&cnt32[b >> 1], 1u << ((b & 1) << 4));
            }
        }
    }

    // ---- 8 dim-tiles x 4 k-steps of mfma_f32_16x16x32_bf16
#pragma unroll
    for (int dt = 0; dt < 8; ++dt) {
        f32x4 acc = {0.f, 0.f, 0.f, 0.f};
        const int od = dt * 16 + (lane & 15);
#pragma unroll
        for (int s = 0; s < 4; ++s) {
            int byte = od * 256 + ((s * 64 + q * 16) ^ ((od & 7) << 4));
            bf16x8 a = *reinterpret_cast<const bf16x8*>(Wl + byte);
            acc = __builtin_amdgcn_mfma_f32_16x16x32_bf16(a, xb[s], acc, 0, 0, 0);
        }
        if (node < N_NODES) {
            unsigned int lo = (unsigned int)f2bf(acc[0]) | ((unsigned int)f2bf(acc[1]) << 16);
            unsigned int hi = (unsigned int)f2bf(acc[2]) | ((unsigned int)f2bf(acc[3]) << 16);
            *reinterpret_cast<uint2*>(h + (size_t)node * DIM + dt * 16 + q * 4) = make_uint2(lo, hi);
        }
    }

    if (Hm16) {
        __syncthreads();
        unsigned short* Hrow = Hm16 + (size_t)blockIdx.x * NB_G;
        for (int i = tid; i < NB_G; i += 256)
            Hrow[i] = (unsigned short)((cnt32[i >> 1] >> ((i & 1) << 4)) & 0xFFFFu);
    }
}

// ---------------- scanAB: per-bucket scan of Hm16 along j + last-block bucket scan ----------------
// 49 blocks x 512 thr. Block g owns buckets g*64+lane (lane-coalesced u16 access);
// the 8 waves split the j range [0,782). Last block scans tot -> boff.
__global__ __launch_bounds__(512) void scanAB_kernel(unsigned short* __restrict__ Hm16,
                                                     int* __restrict__ tot,
                                                     int* __restrict__ boff,
                                                     int* __restrict__ done) {
    __shared__ int part[8 * 64];
    __shared__ int lastFlag;
    int tid = threadIdx.x, g = blockIdx.x;
    int w = tid >> 6, lane = tid & 63;
    int bucket = g * 64 + lane;
    bool bv = bucket < NB_G;
    int j0 = w * 98;
    int j1 = j0 + 98; if (j1 > NJ) j1 = NJ;

    // pass 1: per-(wave,bucket) partial sums
    int ps = 0;
    if (bv) for (int j = j0; j < j1; ++j) ps += Hm16[(size_t)j * NB_G + bucket];
    part[w * 64 + lane] = ps;
    __syncthreads();
    int base = 0, total = 0;
#pragma unroll
    for (int ww = 0; ww < 8; ++ww) {
        int p = part[ww * 64 + lane];
        if (ww < w) base += p;
        total += p;
    }
    if (w == 0 && bv) tot[bucket] = total;

    // pass 2: write exclusive prefix back (u16; bucket total < 512)
    if (bv) {
        int carry = base;
        for (int j = j0; j < j1; ++j) {
            size_t idx = (size_t)j * NB_G + bucket;
            int v = Hm16[idx];
            Hm16[idx] = (unsigned short)carry;
            carry += v;
        }
    }
    __syncthreads();
    if (tid == 0) {
        __threadfence();
        int old = atomicAdd(done, 1);
        lastFlag = (old == (int)gridDim.x - 1) ? 1 : 0;
    }
    __syncthreads();
    if (lastFlag) {
        __threadfence();   // acquire other blocks' tot writes
        if (tid < 64) {
            int carry = 0;
            for (int ch = 0; ch < 49; ++ch) {
                int i = ch * 64 + tid;
                int v = (i < NB_G) ? tot[i] : 0;
                int incl = v;
#pragma unroll
                for (int d = 1; d < 64; d <<= 1) {
                    int t = __shfl_up(incl, d);
                    if (tid >= d) incl += t;
                }
                if (i < NB_G) boff[i] = carry + incl - v;
                carry += __shfl(incl, 63);
            }
            if (tid == 0) { boff[NB_G] = N_EDGES; *done = 0; }
        }
    }
}

// ---------------- scatter: deterministic bucket partition, LDS cursors ----------------
__global__ __launch_bounds__(256) void scatter_kernel(const int* __restrict__ rows,
                                                      const int* __restrict__ cols,
                                                      const float* __restrict__ vals,
                                                      const unsigned short* __restrict__ Hm16,
                                                      const int* __restrict__ boff,
                                                      int2* __restrict__ erec) {
    __shared__ int cl[NB_G];
    int tid = threadIdx.x, j = blockIdx.x;
    const unsigned short* Hrow = Hm16 + (size_t)j * NB_G;
    for (int i = tid; i < NB_G; i += 256) cl[i] = boff[i] + (int)Hrow[i];
    __syncthreads();
    int ebase = j * EPB;
#pragma unroll
    for (int i = 0; i < 3; ++i) {
        int e = ebase + tid + i * 256;
        if (e < N_EDGES) {
            int r = rows[e];
            int slot = atomicAdd(&cl[r >> 4], 1);
            int2 rec;
            rec.x = cols[e] | ((r & 15) << 16);
            rec.y = __float_as_int(vals[e]);
            erec[slot] = rec;
        }
    }
}

// ---------------- gather: 16-node buckets; LDS counting sort + half-wave ushort4 accumulate ----------------
// 3125 blocks x 256 thr (4 waves, 4 nodes/wave). Half-waves split each node's
// edge stream (stride 2); 32 lanes x ushort4 (8B) = 256B = one h-row, so each
// wave-load instruction covers 2 edges. 4-deep unroll; shfl_xor(32) combine.
__global__ __launch_bounds__(256) void gather_kernel(const unsigned short* __restrict__ h,
                                                     const int2* __restrict__ erec,
                                                     const int* __restrict__ boff,
                                                     float* __restrict__ out) {
    __shared__ int2 srt[GCAP];            // 4 KB sorted records
    __shared__ int hist[16];
    __shared__ int cursor[16];
    __shared__ int starts[17];
    int tid = threadIdx.x, b = blockIdx.x;
    int beg = boff[b], end = boff[b + 1];
    int cnt = end - beg;
    int w = tid >> 6, lane = tid & 63;
    int pos = lane & 31;                  // dim group: dims pos*4 .. pos*4+3
    int half = lane >> 5;

    if (tid < 16) hist[tid] = 0;
    __syncthreads();

    if (cnt <= GCAP) {
        // ---- phase 1: stage to registers + 16-bin histogram
        int2 rec[2];
        int  rr[2];
#pragma unroll
        for (int k = 0; k < 2; ++k) {
            int i = tid + k * 256;
            if (i < cnt) {
                rec[k] = erec[beg + i];
                rr[k] = (rec[k].x >> 16) & 15;
                atomicAdd(&hist[rr[k]], 1);
            }
        }
        __syncthreads();
        // ---- phase 2: exclusive scan of the 16 bins
        if (tid < 16) {
            int v = hist[tid], incl = v;
#pragma unroll
            for (int d = 1; d < 16; d <<= 1) {
                int t = __shfl_up(incl, d);
                if (tid >= d) incl += t;
            }
            starts[tid] = incl - v;
            cursor[tid] = incl - v;
            if (tid == 15) starts[16] = incl;
        }
        __syncthreads();
        // ---- phase 3: place into sorted LDS order
#pragma unroll
        for (int k = 0; k < 2; ++k) {
            int i = tid + k * 256;
            if (i < cnt) {
                int p2 = atomicAdd(&cursor[rr[k]], 1);
                srt[p2] = rec[k];
            }
        }
        __syncthreads();
        // ---- phase 4: 4 nodes per wave, half-wave streams, 4-deep unroll
        for (int t0 = 0; t0 < 4; ++t0) {
            int t = w * 4 + t0;
            int node = b * 16 + t;        // always < 50000 (3125*16 exact)
            int s0 = starts[t], s1 = starts[t + 1];
            float a0 = 0.f, a1 = 0.f, a2 = 0.f, a3 = 0.f;
            int i = s0 + half;
            for (; i + 6 < s1; i += 8) {
                int2 r0 = srt[i], r1 = srt[i + 2], r2 = srt[i + 4], r3 = srt[i + 6];
                ushort4 h0 = *((const ushort4*)(h + (size_t)(r0.x & 0xFFFF) * DIM) + pos);
                ushort4 h1 = *((const ushort4*)(h + (size_t)(r1.x & 0xFFFF) * DIM) + pos);
                ushort4 h2 = *((const ushort4*)(h + (size_t)(r2.x & 0xFFFF) * DIM) + pos);
                ushort4 h3 = *((const ushort4*)(h + (size_t)(r3.x & 0xFFFF) * DIM) + pos);
                float v0 = __int_as_float(r0.y), v1 = __int_as_float(r1.y);
                float v2 = __int_as_float(r2.y), v3 = __int_as_float(r3.y);
                a0 += v0 * bf2f(h0.x) + v1 * bf2f(h1.x) + v2 * bf2f(h2.x) + v3 * bf2f(h3.x);
                a1 += v0 * bf2f(h0.y) + v1 * bf2f(h1.y) + v2 * bf2f(h2.y) + v3 * bf2f(h3.y);
                a2 += v0 * bf2f(h0.z) + v1 * bf2f(h1.z) + v2 * bf2f(h2.z) + v3 * bf2f(h3.z);
                a3 += v0 * bf2f(h0.w) + v1 * bf2f(h1.w) + v2 * bf2f(h2.w) + v3 * bf2f(h3.w);
            }
            for (; i < s1; i += 2) {
                int2 r0 = srt[i];
                ushort4 h0 = *((const ushort4*)(h + (size_t)(r0.x & 0xFFFF) * DIM) + pos);
                float v0 = __int_as_float(r0.y);
                a0 += v0 * bf2f(h0.x);
                a1 += v0 * bf2f(h0.y);
                a2 += v0 * bf2f(h0.z);
                a3 += v0 * bf2f(h0.w);
            }
            a0 += __shfl_xor(a0, 32);
            a1 += __shfl_xor(a1, 32);
            a2 += __shfl_xor(a2, 32);
            a3 += __shfl_xor(a3, 32);
            if (half == 0) {
                float4 o;
                o.x = fmaxf(a0, 0.f);
                o.y = fmaxf(a1, 0.f);
                o.z = fmaxf(a2, 0.f);
                o.w = fmaxf(a3, 0.f);
                *reinterpret_cast<float4*>(&out[(size_t)node * DIM + pos * 4]) = o;
            }
        }
    } else {
        // ---- oversize-bucket fallback (statistically unreachable, kept for correctness)
        for (int t0 = 0; t0 < 4; ++t0) {
            int t = w * 4 + t0;
            int node = b * 16 + t;
            float a0 = 0.f, a1 = 0.f, a2 = 0.f, a3 = 0.f;
            for (int i = half; i < cnt; i += 2) {
                int2 r = erec[beg + i];
                if (((r.x >> 16) & 15) == t) {
                    ushort4 hv = *((const ushort4*)(h + (size_t)(r.x & 0xFFFF) * DIM) + pos);
                    float v = __int_as_float(r.y);
                    a0 += v * bf2f(hv.x);
                    a1 += v * bf2f(hv.y);
                    a2 += v * bf2f(hv.z);
                    a3 += v * bf2f(hv.w);
                }
            }
            a0 += __shfl_xor(a0, 32);
            a1 += __shfl_xor(a1, 32);
            a2 += __shfl_xor(a2, 32);
            a3 += __shfl_xor(a3, 32);
            if (half == 0) {
                float4 o;
                o.x = fmaxf(a0, 0.f);
                o.y = fmaxf(a1, 0.f);
                o.z = fmaxf(a2, 0.f);
                o.w = fmaxf(a3, 0.f);
                *reinterpret_cast<float4*>(&out[(size_t)node * DIM + pos * 4]) = o;
            }
        }
    }
}

// ---------------- fallback: atomic scatter over bf16 h ----------------
__global__ __launch_bounds__(256) void edge_kernel(const unsigned short* __restrict__ h,
                                                   const float* __restrict__ vals,
                                                   const int* __restrict__ rows,
                                                   const int* __restrict__ cols,
                                                   float* __restrict__ out) {
    long long gid = (long long)blockIdx.x * 256 + threadIdx.x;
    int e    = (int)(gid >> 5);
    int lane = (int)(gid & 31);
    if (e >= N_EDGES) return;
    int r = rows[e];
    int c = cols[e];
    float v = vals[e];
    ushort4 hv = *((const ushort4*)(h + (size_t)c * DIM) + lane);
    float* op = &out[(size_t)r * DIM + lane * 4];
    atomicAdd(op + 0, v * bf2f(hv.x));
    atomicAdd(op + 1, v * bf2f(hv.y));
    atomicAdd(op + 2, v * bf2f(hv.z));
    atomicAdd(op + 3, v * bf2f(hv.w));
}

__global__ __launch_bounds__(256) void relu_kernel(float* __restrict__ out) {
    int i = blockIdx.x * 256 + threadIdx.x;
    float4* p = reinterpret_cast<float4*>(out) + i;
    float4 v = *p;
    v.x = fmaxf(v.x, 0.f);
    v.y = fmaxf(v.y, 0.f);
    v.z = fmaxf(v.z, 0.f);
    v.w = fmaxf(v.w, 0.f);
    *p = v;
}

extern "C" void kernel_launch(void* const* d_in, const int* in_sizes, int n_in,
                              void* d_out, int out_size, void* d_ws, size_t ws_size,
                              hipStream_t stream) {
    const float* x    = (const float*)d_in[0];
    const float* W    = (const float*)d_in[1];
    const float* vals = (const float*)d_in[2];
    const int*   rows = (const int*)d_in[3];
    const int*   cols = (const int*)d_in[4];
    float* out = (float*)d_out;

    // ---- workspace layout ----
    unsigned short* h = (unsigned short*)d_ws;                    // 12.8 MB bf16
    int2* erec = (int2*)(h + (size_t)N_NODES * DIM);              // 4.8 MB
    unsigned short* Hm16 = (unsigned short*)(erec + N_EDGES);     // 782*3125*2 = 4.89 MB
    int*  tot  = (int*)(Hm16 + (size_t)NJ * NB_G);                // 3125 ints
    int*  boff = tot + NB_G;                                      // 3126 ints
    int*  done = boff + (NB_G + 1);                               // 1 int
    size_t need = (size_t)((char*)(done + 1) - (char*)d_ws);

    if (ws_size >= need) {
        gemm_kernel<<<NJ, 256, 0, stream>>>(x, W, h, rows, Hm16, done);
        scanAB_kernel<<<(NB_G + 63) / 64, 512, 0, stream>>>(Hm16, tot, boff, done);
        scatter_kernel<<<NJ, 256, 0, stream>>>(rows, cols, vals, Hm16, boff, erec);
        gather_kernel<<<NB_G, 256, 0, stream>>>(h, erec, boff, out);
    } else {
        // fallback: atomic scatter path (needs only h)
        gemm_kernel<<<NJ, 256, 0, stream>>>(x, W, h, nullptr, nullptr, nullptr);
        hipMemsetAsync(d_out, 0, (size_t)N_NODES * DIM * sizeof(float), stream);
        edge_kernel<<<(N_EDGES * 32) / 256, 256, 0, stream>>>(h, vals, rows, cols, out);
        relu_kernel<<<(N_NODES * DIM / 4) / 256, 256, 0, stream>>>(out);
    }
}

// Round 13
// 68.557 us; speedup vs baseline: 1.6637x; 1.6637x over previous
//
#include <hip/hip_runtime.h>

#define N_NODES 50000
#define N_EDGES 600000
#define DIM 128
#define NB 782                 // 64-node buckets (= gather blocks)
#define EPB 768                // edges per partition block: 782*768 = 600576
#define GCAP 2048              // gather LDS sort capacity (mean 767, sd 28)

typedef short bf16x8 __attribute__((ext_vector_type(8)));
typedef float f32x4 __attribute__((ext_vector_type(4)));

__device__ __forceinline__ float bf2f(unsigned short u) {
    union { unsigned int i; float f; } x; x.i = ((unsigned int)u) << 16; return x.f;
}
__device__ __forceinline__ unsigned short f2bf(float f) {
    union { float f; unsigned int i; } x; x.f = f;
    unsigned int r = x.i + 0x7FFFu + ((x.i >> 16) & 1u);   // RNE
    return (unsigned short)(r >> 16);
}

// ---------------- MFMA GEMM + fused bucket histogram (r8-proven) ----------------
#define GEMM_BLOCKS NB           // ceil(50000/64) == 782 == NB

__global__ __launch_bounds__(256) void gemm_kernel(const float* __restrict__ x,
                                                   const float* __restrict__ W,
                                                   unsigned short* __restrict__ h,
                                                   const int* __restrict__ rows,
                                                   int* __restrict__ Hm) {
    __shared__ unsigned char Wl[128 * 256];   // bf16[128 dims][128 k], swizzled
    __shared__ int cntL[NB];
    const int tid = threadIdx.x;

    if (Hm) {
        for (int i = tid; i < NB; i += 256) cntL[i] = 0;
    }

    // ---- stage W -> LDS bf16 (swizzled)
#pragma unroll
    for (int i = 0; i < 16; ++i) {
        int c  = tid + i * 256;
        int od = c >> 5;
        int kg = c & 31;
        float4 w = *((const float4*)(W + od * DIM) + kg);
        unsigned int lo = (unsigned int)f2bf(w.x) | ((unsigned int)f2bf(w.y) << 16);
        unsigned int hi = (unsigned int)f2bf(w.z) | ((unsigned int)f2bf(w.w) << 16);
        int byte = od * 256 + ((kg * 8) ^ ((od & 7) << 4));
        *reinterpret_cast<uint2*>(Wl + byte) = make_uint2(lo, hi);
    }

    // ---- load + convert this wave's x rows (node = lane&15, k-slot = lane>>4)
    const int lane = tid & 63;
    const int wv   = tid >> 6;
    const int q    = lane >> 4;
    const int node = blockIdx.x * 64 + wv * 16 + (lane & 15);
    const int ncl  = node < N_NODES ? node : N_NODES - 1;

    bf16x8 xb[4];
#pragma unroll
    for (int s = 0; s < 4; ++s) {
        const float* xp = x + (size_t)ncl * DIM + s * 32 + q * 8;
        float4 x0 = *(const float4*)(xp);
        float4 x1 = *(const float4*)(xp + 4);
        bf16x8 v;
        v[0] = (short)f2bf(x0.x); v[1] = (short)f2bf(x0.y);
        v[2] = (short)f2bf(x0.z); v[3] = (short)f2bf(x0.w);
        v[4] = (short)f2bf(x1.x); v[5] = (short)f2bf(x1.y);
        v[6] = (short)f2bf(x1.z); v[7] = (short)f2bf(x1.w);
        xb[s] = v;
    }

    __syncthreads();   // cntL zeroed + W staged

    // ---- fused histogram: LDS atomics only
    if (Hm) {
        int ebase = blockIdx.x * EPB;
#pragma unroll
        for (int i = 0; i < 3; ++i) {
            int e = ebase + tid + i * 256;
            if (e < N_EDGES) atomicAdd(&cntL[rows[e] >> 6], 1);
        }
    }

    // ---- 8 dim-tiles x 4 k-steps of mfma_f32_16x16x32_bf16
#pragma unroll
    for (int dt = 0; dt < 8; ++dt) {
        f32x4 acc = {0.f, 0.f, 0.f, 0.f};
        const int od = dt * 16 + (lane & 15);
#pragma unroll
        for (int s = 0; s < 4; ++s) {
            int byte = od * 256 + ((s * 64 + q * 16) ^ ((od & 7) << 4));
            bf16x8 a = *reinterpret_cast<const bf16x8*>(Wl + byte);
            acc = __builtin_amdgcn_mfma_f32_16x16x32_bf16(a, xb[s], acc, 0, 0, 0);
        }
        if (node < N_NODES) {
            unsigned int lo = (unsigned int)f2bf(acc[0]) | ((unsigned int)f2bf(acc[1]) << 16);
            unsigned int hi = (unsigned int)f2bf(acc[2]) | ((unsigned int)f2bf(acc[3]) << 16);
            *reinterpret_cast<uint2*>(h + (size_t)node * DIM + dt * 16 + q * 4) = make_uint2(lo, hi);
        }
    }

    if (Hm) {
        __syncthreads();
        int* Hrow = Hm + (size_t)blockIdx.x * NB;
        for (int i = tid; i < NB; i += 256) Hrow[i] = cntL[i];   // coalesced 3KB
    }
}

// ---------------- scanA: per-bucket exclusive scan of H[j][b] along j ----------------
__global__ __launch_bounds__(256) void scanA_kernel(int* __restrict__ Hm,
                                                    int* __restrict__ tot) {
    int gw   = (blockIdx.x * 256 + threadIdx.x) >> 6;   // bucket
    int lane = threadIdx.x & 63;
    if (gw >= NB) return;
    int carry = 0;
    for (int ch = 0; ch < 13; ++ch) {
        int j = ch * 64 + lane;
        int v = (j < NB) ? Hm[(size_t)j * NB + gw] : 0;
        int incl = v;
#pragma unroll
        for (int d = 1; d < 64; d <<= 1) {
            int t = __shfl_up(incl, d);
            if (lane >= d) incl += t;
        }
        if (j < NB) Hm[(size_t)j * NB + gw] = carry + incl - v;
        carry += __shfl(incl, 63);
    }
    if (lane == 0) tot[gw] = carry;
}

// ---------------- scanB: exclusive scan of bucket totals -> boff ----------------
__global__ __launch_bounds__(1024) void scanB_kernel(const int* __restrict__ tot,
                                                     int* __restrict__ boff) {
    __shared__ int s[1024];
    int t = threadIdx.x;
    int v = (t < NB) ? tot[t] : 0;
    s[t] = v;
    __syncthreads();
    for (int d = 1; d < 1024; d <<= 1) {
        int a = (t >= d) ? s[t - d] : 0;
        __syncthreads();
        s[t] += a;
        __syncthreads();
    }
    if (t < NB) boff[t] = s[t] - v;
    if (t == 0) boff[NB] = N_EDGES;
}

// ---------------- scatter: deterministic bucket partition, LDS cursors ----------------
__global__ __launch_bounds__(256) void scatter_kernel(const int* __restrict__ rows,
                                                      const int* __restrict__ cols,
                                                      const float* __restrict__ vals,
                                                      const int* __restrict__ Hm,
                                                      const int* __restrict__ boff,
                                                      int2* __restrict__ erec) {
    __shared__ int cl[NB];
    int tid = threadIdx.x, j = blockIdx.x;
    const int* Hrow = Hm + (size_t)j * NB;
    for (int i = tid; i < NB; i += 256) cl[i] = boff[i] + Hrow[i];
    __syncthreads();
    int ebase = j * EPB;
#pragma unroll
    for (int i = 0; i < 3; ++i) {
        int e = ebase + tid + i * 256;
        if (e < N_EDGES) {
            int r = rows[e];
            int slot = atomicAdd(&cl[r >> 6], 1);
            int2 rec;
            rec.x = cols[e] | ((r & 63) << 16);
            rec.y = __float_as_int(vals[e]);
            erec[slot] = rec;
        }
    }
}

// ---------------- gather: LDS counting sort + half-wave ushort4 accumulate (r8-proven) ----------------
// 512 threads (8 waves, 8 nodes/wave). Half-waves split each node's stream
// (stride 2): 32 lanes x ushort4 (8B) = 256B = one h-row -> 2 edges per
// wave-load instruction. Tiered unroll: 4-deep, then 2-deep (NEW vs r8 — the
// 4-deep tier needs >=8 left and rarely fires at deg~12), then serial tail.
__global__ __launch_bounds__(512) void gather_kernel(const unsigned short* __restrict__ h,
                                                     const int2* __restrict__ erec,
                                                     const int* __restrict__ boff,
                                                     float* __restrict__ out) {
    __shared__ int2 srt[GCAP];            // 16 KB sorted records
    __shared__ int hist[64];
    __shared__ int cursor[64];
    __shared__ int starts[65];
    int tid = threadIdx.x, b = blockIdx.x;
    int beg = boff[b], end = boff[b + 1];
    int cnt = end - beg;
    int w = tid >> 6, lane = tid & 63;
    int pos = lane & 31;                  // dim group: dims pos*4 .. pos*4+3
    int half = lane >> 5;

    if (tid < 64) hist[tid] = 0;
    __syncthreads();

    if (cnt <= GCAP) {
        // ---- phase 1: stage to registers + 64-bin histogram
        int2 rec[4];
        int  rr[4];
#pragma unroll
        for (int k = 0; k < 4; ++k) {
            int i = tid + k * 512;
            if (i < cnt) {
                rec[k] = erec[beg + i];
                rr[k] = (rec[k].x >> 16) & 63;
                atomicAdd(&hist[rr[k]], 1);
            }
        }
        __syncthreads();
        // ---- phase 2: exclusive scan of the 64 bins (wave 0)
        if (tid < 64) {
            int v = hist[tid], incl = v;
#pragma unroll
            for (int d = 1; d < 64; d <<= 1) {
                int t = __shfl_up(incl, d);
                if (tid >= d) incl += t;
            }
            starts[tid] = incl - v;
            cursor[tid] = incl - v;
            if (tid == 63) starts[64] = incl;
        }
        __syncthreads();
        // ---- phase 3: place into sorted LDS order
#pragma unroll
        for (int k = 0; k < 4; ++k) {
            int i = tid + k * 512;
            if (i < cnt) {
                int p2 = atomicAdd(&cursor[rr[k]], 1);
                srt[p2] = rec[k];
            }
        }
        __syncthreads();
        // ---- phase 4: 8 nodes/wave, half-wave streams, tiered unroll
        for (int t0 = 0; t0 < 8; ++t0) {
            int t = w * 8 + t0;
            int node = b * 64 + t;
            int s0 = starts[t], s1 = starts[t + 1];
            float a0 = 0.f, a1 = 0.f, a2 = 0.f, a3 = 0.f;
            int i = s0 + half;
            for (; i + 6 < s1; i += 8) {
                int2 r0 = srt[i], r1 = srt[i + 2], r2 = srt[i + 4], r3 = srt[i + 6];
                ushort4 h0 = *((const ushort4*)(h + (size_t)(r0.x & 0xFFFF) * DIM) + pos);
                ushort4 h1 = *((const ushort4*)(h + (size_t)(r1.x & 0xFFFF) * DIM) + pos);
                ushort4 h2 = *((const ushort4*)(h + (size_t)(r2.x & 0xFFFF) * DIM) + pos);
                ushort4 h3 = *((const ushort4*)(h + (size_t)(r3.x & 0xFFFF) * DIM) + pos);
                float v0 = __int_as_float(r0.y), v1 = __int_as_float(r1.y);
                float v2 = __int_as_float(r2.y), v3 = __int_as_float(r3.y);
                a0 += v0 * bf2f(h0.x) + v1 * bf2f(h1.x) + v2 * bf2f(h2.x) + v3 * bf2f(h3.x);
                a1 += v0 * bf2f(h0.y) + v1 * bf2f(h1.y) + v2 * bf2f(h2.y) + v3 * bf2f(h3.y);
                a2 += v0 * bf2f(h0.z) + v1 * bf2f(h1.z) + v2 * bf2f(h2.z) + v3 * bf2f(h3.z);
                a3 += v0 * bf2f(h0.w) + v1 * bf2f(h1.w) + v2 * bf2f(h2.w) + v3 * bf2f(h3.w);
            }
            for (; i + 2 < s1; i += 4) {   // NEW: 2-deep tier, fires at deg>=5
                int2 r0 = srt[i], r1 = srt[i + 2];
                ushort4 h0 = *((const ushort4*)(h + (size_t)(r0.x & 0xFFFF) * DIM) + pos);
                ushort4 h1 = *((const ushort4*)(h + (size_t)(r1.x & 0xFFFF) * DIM) + pos);
                float v0 = __int_as_float(r0.y), v1 = __int_as_float(r1.y);
                a0 += v0 * bf2f(h0.x) + v1 * bf2f(h1.x);
                a1 += v0 * bf2f(h0.y) + v1 * bf2f(h1.y);
                a2 += v0 * bf2f(h0.z) + v1 * bf2f(h1.z);
                a3 += v0 * bf2f(h0.w) + v1 * bf2f(h1.w);
            }
            for (; i < s1; i += 2) {
                int2 r0 = srt[i];
                ushort4 h0 = *((const ushort4*)(h + (size_t)(r0.x & 0xFFFF) * DIM) + pos);
                float v0 = __int_as_float(r0.y);
                a0 += v0 * bf2f(h0.x);
                a1 += v0 * bf2f(h0.y);
                a2 += v0 * bf2f(h0.z);
                a3 += v0 * bf2f(h0.w);
            }
            // combine the two halves
            a0 += __shfl_xor(a0, 32);
            a1 += __shfl_xor(a1, 32);
            a2 += __shfl_xor(a2, 32);
            a3 += __shfl_xor(a3, 32);
            if (half == 0 && node < N_NODES) {
                float4 o;
                o.x = fmaxf(a0, 0.f);
                o.y = fmaxf(a1, 0.f);
                o.z = fmaxf(a2, 0.f);
                o.w = fmaxf(a3, 0.f);
                *reinterpret_cast<float4*>(&out[(size_t)node * DIM + pos * 4]) = o;
            }
        }
    } else {
        // ---- oversize-bucket fallback (statistically unreachable, kept for correctness)
        for (int t0 = 0; t0 < 8; ++t0) {
            int t = w * 8 + t0;
            int node = b * 64 + t;
            float a0 = 0.f, a1 = 0.f, a2 = 0.f, a3 = 0.f;
            for (int i = half; i < cnt; i += 2) {
                int2 r = erec[beg + i];
                if (((r.x >> 16) & 63) == t) {
                    ushort4 hv = *((const ushort4*)(h + (size_t)(r.x & 0xFFFF) * DIM) + pos);
                    float v = __int_as_float(r.y);
                    a0 += v * bf2f(hv.x);
                    a1 += v * bf2f(hv.y);
                    a2 += v * bf2f(hv.z);
                    a3 += v * bf2f(hv.w);
                }
            }
            a0 += __shfl_xor(a0, 32);
            a1 += __shfl_xor(a1, 32);
            a2 += __shfl_xor(a2, 32);
            a3 += __shfl_xor(a3, 32);
            if (half == 0 && node < N_NODES) {
                float4 o;
                o.x = fmaxf(a0, 0.f);
                o.y = fmaxf(a1, 0.f);
                o.z = fmaxf(a2, 0.f);
                o.w = fmaxf(a3, 0.f);
                *reinterpret_cast<float4*>(&out[(size_t)node * DIM + pos * 4]) = o;
            }
        }
    }
}

// ---------------- fallback: atomic scatter over bf16 h ----------------
__global__ __launch_bounds__(256) void edge_kernel(const unsigned short* __restrict__ h,
                                                   const float* __restrict__ vals,
                                                   const int* __restrict__ rows,
                                                   const int* __restrict__ cols,
                                                   float* __restrict__ out) {
    long long gid = (long long)blockIdx.x * 256 + threadIdx.x;
    int e    = (int)(gid >> 5);
    int lane = (int)(gid & 31);
    if (e >= N_EDGES) return;
    int r = rows[e];
    int c = cols[e];
    float v = vals[e];
    ushort4 hv = *((const ushort4*)(h + (size_t)c * DIM) + lane);
    float* op = &out[(size_t)r * DIM + lane * 4];
    atomicAdd(op + 0, v * bf2f(hv.x));
    atomicAdd(op + 1, v * bf2f(hv.y));
    atomicAdd(op + 2, v * bf2f(hv.z));
    atomicAdd(op + 3, v * bf2f(hv.w));
}

__global__ __launch_bounds__(256) void relu_kernel(float* __restrict__ out) {
    int i = blockIdx.x * 256 + threadIdx.x;
    float4* p = reinterpret_cast<float4*>(out) + i;
    float4 v = *p;
    v.x = fmaxf(v.x, 0.f);
    v.y = fmaxf(v.y, 0.f);
    v.z = fmaxf(v.z, 0.f);
    v.w = fmaxf(v.w, 0.f);
    *p = v;
}

extern "C" void kernel_launch(void* const* d_in, const int* in_sizes, int n_in,
                              void* d_out, int out_size, void* d_ws, size_t ws_size,
                              hipStream_t stream) {
    const float* x    = (const float*)d_in[0];
    const float* W    = (const float*)d_in[1];
    const float* vals = (const float*)d_in[2];
    const int*   rows = (const int*)d_in[3];
    const int*   cols = (const int*)d_in[4];
    float* out = (float*)d_out;

    // ---- workspace layout ----
    unsigned short* h = (unsigned short*)d_ws;               // 12.8 MB bf16
    int2* erec = (int2*)(h + (size_t)N_NODES * DIM);         // 4.8 MB
    int*  Hm   = (int*)(erec + N_EDGES);                     // 2.45 MB
    int*  tot  = Hm + (size_t)NB * NB;                       // 782
    int*  boff = tot + NB;                                   // 783
    size_t need = (size_t)((char*)(boff + NB + 1) - (char*)d_ws);

    if (ws_size >= need) {
        gemm_kernel<<<GEMM_BLOCKS, 256, 0, stream>>>(x, W, h, rows, Hm);
        scanA_kernel<<<(NB * 64 + 255) / 256, 256, 0, stream>>>(Hm, tot);
        scanB_kernel<<<1, 1024, 0, stream>>>(tot, boff);
        scatter_kernel<<<NB, 256, 0, stream>>>(rows, cols, vals, Hm, boff, erec);
        gather_kernel<<<NB, 512, 0, stream>>>(h, erec, boff, out);
    } else {
        // fallback: atomic scatter path (needs only h)
        gemm_kernel<<<GEMM_BLOCKS, 256, 0, stream>>>(x, W, h, nullptr, nullptr);
        hipMemsetAsync(d_out, 0, (size_t)N_NODES * DIM * sizeof(float), stream);
        edge_kernel<<<(N_EDGES * 32) / 256, 256, 0, stream>>>(h, vals, rows, cols, out);
        relu_kernel<<<(N_NODES * DIM / 4) / 256, 256, 0, stream>>>(out);
    }
}